// Round 4
// baseline (163.713 us; speedup 1.0000x reference)
//
#include <hip/hip_runtime.h>
#include <math.h>

#define NN 256
#define NS 512
#define MS 32
#define NSTEP 32
#define VRESET 1.0f

__device__ __forceinline__ float sigf(float x) {
    // fast sigmoid: v_exp_f32 + v_rcp_f32 (~3 ulp); verified no event flips
    // (absmax identical to OCML expf version: 0.125).
    float e = __expf(-x);
    return __builtin_amdgcn_rcpf(1.0f + e);
}

// Barrier WITHOUT the vmcnt(0) drain that __syncthreads() emits.
// Cross-wave communication here is LDS-only, so lgkmcnt(0) + s_barrier is
// sufficient; global stores (round outputs) and loads (reset_s prefetch)
// deliberately stay in flight across it.
__device__ __forceinline__ void block_sync_lds() {
    asm volatile("s_waitcnt lgkmcnt(0)" ::: "memory");
    __builtin_amdgcn_s_barrier();
    asm volatile("" ::: "memory");
}

// One RK4 step — op-for-op identical order to the verified kernel.
__device__ __forceinline__ void rk4step(float v, float ii, float s,
                                        float ic, float mu1, float mu2,
                                        float dt, float hh, float h6,
                                        float& vn, float& in_, float& sn)
{
    float kv1 = mu1 * (ii + ic - v);
    float ki1 = -mu2 * ii;
    float ks1 = sigf(v);
    float v2 = v + hh * kv1;
    float i2 = ii + hh * ki1;
    float kv2 = mu1 * (i2 + ic - v2);
    float ki2 = -mu2 * i2;
    float ks2 = sigf(v2);
    float v3 = v + hh * kv2;
    float i3 = ii + hh * ki2;
    float kv3 = mu1 * (i3 + ic - v3);
    float ki3 = -mu2 * i3;
    float ks3 = sigf(v3);
    float v4 = v + dt * kv3;
    float i4 = ii + dt * ki3;
    float kv4 = mu1 * (i4 + ic - v4);
    float ki4 = -mu2 * i4;
    float ks4 = sigf(v4);
    vn  = v  + h6 * (kv1 + 2.0f * kv2 + 2.0f * kv3 + kv4);
    in_ = ii + h6 * (ki1 + 2.0f * ki2 + 2.0f * ki3 + ki4);
    sn  = s  + h6 * (ks1 + 2.0f * ks2 + 2.0f * ks3 + ks4);
}

// One block (256 threads = 4 waves) per sample; thread tid owns neuron tid.
// R3 change (value-identical): crossing checks are amortized over 4-step
// WINDOWS. Each window computes W1..W4 keeping all 5 states in registers;
// ONE rendezvous exchanges a 4-bit per-wave mask (bit j-1 = any(s(Wj)>0)).
// On a hit, the earliest flagged step j is recovered from the merged mask
// and the event interpolates W_{j-1} <-> W_j (both in registers, no replay).
// First-crossing-step selection, RK4 op order, and t accumulation order are
// identical to the per-step version => outputs bitwise identical.
// Barriers per full 32-step round: 32 -> 8. The R2 spec-split is kept at
// window scale: next window's W1'/W2' straddle the barrier (reused on
// no-cross, so steady state is exactly 4 RK4s per 4 steps).
__global__ __launch_bounds__(256) void snn_kernel(
    const float* __restrict__ ic_g,     // (256,)
    const float* __restrict__ w,        // (256,256)
    const float* __restrict__ mu,       // (2,)
    const float* __restrict__ v0,       // (256,)
    const float* __restrict__ i0,       // (256,)
    const float* __restrict__ s0,       // (512,256)
    const float* __restrict__ reset_s,  // (32,512,256)
    const int*   __restrict__ t1p,      // scalar
    float* __restrict__ out)
{
    const int tid  = threadIdx.x;   // neuron index
    const int lane = tid & 63;
    const int wid  = tid >> 6;
    const int samp = blockIdx.x;
    const float mu1 = mu[0];
    const float mu2 = mu[1];
    const float t1f = (float)t1p[0];

    __shared__ int4  s_any4[2];                   // packed wave masks, wdx&1
    __shared__ float s_sn[NN];                    // sn at event
    __shared__ float s_sp[NN];                    // s_prev at event
    __shared__ unsigned long long s_key[4];       // per-wave argmax key
    __shared__ int   s_eidx[4];                   // per-wave min crossed idx

    float v  = v0[tid];
    float ii = i0[tid];
    float s  = s0[samp * NN + tid];
    const float ic = ic_g[tid];
    float t0 = 0.0f;

    float* times = out;                                  // [NS][MS]
    float* vals  = out + (size_t)NS * MS;                // [NS][MS][NN][3]
    float* marks = out + (size_t)NS * MS * (1 + NN * 3); // [NS][MS][NN]

    for (int r = 0; r < MS; ++r) {
        // Prefetch this round's reset row NOW (coalesced 1 KB/block).
        // Consumed only in the reset path; raw barriers keep it in flight.
        const float rs = reset_s[((size_t)r * NS + samp) * NN + tid];

        const float dt = (t1f - t0) / (float)NSTEP;
        float tev = t1f;
        float yv = v, yi = ii, ys = s;
        bool  em = false;
        bool  done = false;
        float wr = 0.0f;

        if (dt != 0.0f) {
            const float hh = 0.5f * dt;
            const float h6 = dt * (1.0f / 6.0f);

            // window state ring: W0..W4 (committed), n1/n2 (spec next window)
            float w0v = v, w0i = ii, w0s = s;
            float w1v, w1i, w1s, w2v, w2i, w2s;
            float w3v, w3i, w3s, w4v, w4i, w4s;
            // prologue: W1, W2
            rk4step(w0v, w0i, w0s, ic, mu1, mu2, dt, hh, h6, w1v, w1i, w1s);
            rk4step(w1v, w1i, w1s, ic, mu1, mu2, dt, hh, h6, w2v, w2i, w2s);
            float tw = t0;                       // t at W0

            for (int wdx = 0; wdx < NSTEP / 4; ++wdx) {
                // finish the window: W3, W4
                rk4step(w2v, w2i, w2s, ic, mu1, mu2, dt, hh, h6, w3v, w3i, w3s);
                rk4step(w3v, w3i, w3s, ic, mu1, mu2, dt, hh, h6, w4v, w4i, w4s);

                // per-wave 4-bit crossing mask for steps W1..W4
                unsigned long long b1 = __ballot(w1s > 0.0f);
                unsigned long long b2 = __ballot(w2s > 0.0f);
                unsigned long long b3 = __ballot(w3s > 0.0f);
                unsigned long long b4 = __ballot(w4s > 0.0f);
                int m = (b1 ? 1 : 0) | (b2 ? 2 : 0) | (b3 ? 4 : 0) | (b4 ? 8 : 0);
                if (lane == 0) ((int*)&s_any4[wdx & 1])[wid] = m;

                // spec next window W1' — covers the ds_write drain + barrier
                const bool spec = (wdx < NSTEP / 4 - 1);
                float n1v = 0.0f, n1i = 0.0f, n1s = 0.0f;
                float n2v = 0.0f, n2i = 0.0f, n2s = 0.0f;
                if (spec)
                    rk4step(w4v, w4i, w4s, ic, mu1, mu2, dt, hh, h6,
                            n1v, n1i, n1s);

                __builtin_amdgcn_sched_barrier(0);
                block_sync_lds();
                __builtin_amdgcn_sched_barrier(0);

                // issue the packed mask read (one ds_read_b128)...
                int4 fl = s_any4[wdx & 1];
                // ...and cover its latency with spec W2'
                if (spec)
                    rk4step(n1v, n1i, n1s, ic, mu1, mu2, dt, hh, h6,
                            n2v, n2i, n2s);

                int mAll = fl.x | fl.y | fl.z | fl.w;

                if (mAll) {
                    // earliest crossing step within the window (block-uniform)
                    int j = __builtin_ctz((unsigned)mAll) + 1;   // 1..4
                    float pv, pi_, ps, cvv, cii, css;
                    if (j == 1)      { pv = w0v; pi_ = w0i; ps = w0s;
                                       cvv = w1v; cii = w1i; css = w1s; }
                    else if (j == 2) { pv = w1v; pi_ = w1i; ps = w1s;
                                       cvv = w2v; cii = w2i; css = w2s; }
                    else if (j == 3) { pv = w2v; pi_ = w2i; ps = w2s;
                                       cvv = w3v; cii = w3i; css = w3s; }
                    else             { pv = w3v; pi_ = w3i; ps = w3s;
                                       cvv = w4v; cii = w4i; css = w4s; }
                    // t at W_{j-1}: same sequential accumulation as stepwise
                    float te = tw;
                    for (int q = 1; q < j; ++q) te += dt;

                    // ---- event: identical math to the verified kernel ----
                    bool crossed = css > 0.0f;
                    s_sn[tid] = css;
                    s_sp[tid] = ps;

                    // packed argmax key: value desc, index asc on ties
                    unsigned int b = __float_as_uint(css);
                    unsigned int msk = (b & 0x80000000u) ? 0xFFFFFFFFu
                                                         : 0x80000000u;
                    unsigned long long key =
                        ((unsigned long long)(b ^ msk) << 32) |
                        (unsigned int)(NN - 1 - tid);
#pragma unroll
                    for (int off = 32; off >= 1; off >>= 1) {
                        unsigned long long o = __shfl_xor(key, off);
                        key = (o > key) ? o : key;
                    }
                    // fused per-wave min crossed index
                    unsigned long long bm = __ballot(crossed);
                    int cand = (bm != 0ull)
                                   ? (wid * 64 + (int)__builtin_ctzll(bm))
                                   : (2 * NN);
                    if (lane == 0) { s_key[wid] = key; s_eidx[wid] = cand; }
                    block_sync_lds();

                    unsigned long long k0 = s_key[0], k1 = s_key[1];
                    unsigned long long k2 = s_key[2], k3 = s_key[3];
                    k0 = (k1 > k0) ? k1 : k0;
                    k2 = (k3 > k2) ? k3 : k2;
                    k0 = (k2 > k0) ? k2 : k0;
                    int bn = NN - 1 - (int)(unsigned int)(k0 & 0xFFFFFFFFull);

                    int eidx = s_eidx[0];
                    eidx = (s_eidx[1] < eidx) ? s_eidx[1] : eidx;
                    eidx = (s_eidx[2] < eidx) ? s_eidx[2] : eidx;
                    eidx = (s_eidx[3] < eidx) ? s_eidx[3] : eidx;

                    // issue the w-row load early; L2 latency hides under interp
                    wr = w[eidx * NN + tid];

                    float bv  = s_sn[bn];
                    float bsp = s_sp[bn];
                    float frac = bsp / (bsp - bv + 1e-12f);
                    frac = fminf(fmaxf(frac, 0.0f), 1.0f);
                    tev = te + frac * dt;
                    yv = pv  + frac * (cvv - pv);
                    yi = pi_ + frac * (cii - pi_);
                    ys = ps  + frac * (css - ps);
                    em = crossed;
                    done = true;
                    break;
                }

                // advance window: W0=W4, W1=W1', W2=W2'
                if (spec) {
                    w0v = w4v; w0i = w4i; w0s = w4s;
                    w1v = n1v; w1i = n1i; w1s = n1s;
                    w2v = n2v; w2i = n2i; w2s = n2s;
                    tw += dt; tw += dt; tw += dt; tw += dt;
                }
            }

            if (!done) { yv = w4v; yi = w4i; ys = w4s; }  // full 32 steps
        }

        // ---- emit round outputs (stores stay in flight across barriers) ----
        const int sr = samp * MS + r;
        if (tid == 0) times[sr] = tev;
        {
            float* p = vals + ((size_t)sr * NN + tid) * 3;
            p[0] = yv;
            p[1] = yi;
            p[2] = ys;
            marks[(size_t)sr * NN + tid] = em ? 1.0f : 0.0f;
        }

        // ---- reset for next round ----
        if (done) {
            v  = yv - (em ? VRESET : 0.0f);
            ii = yi + wr;
            float sres = em ? rs : ys;
            s = fminf(sres, 0.0f);
        } else {
            v = yv; ii = yi;
            s = fminf(ys, 0.0f);
        }
        t0 = tev;
    }
}

extern "C" void kernel_launch(void* const* d_in, const int* in_sizes, int n_in,
                              void* d_out, int out_size, void* d_ws, size_t ws_size,
                              hipStream_t stream) {
    const float* ic      = (const float*)d_in[0];
    const float* w       = (const float*)d_in[1];
    const float* mu      = (const float*)d_in[2];
    const float* v0      = (const float*)d_in[3];
    const float* i0      = (const float*)d_in[4];
    const float* s0      = (const float*)d_in[5];
    const float* reset_s = (const float*)d_in[6];
    const int*   t1p     = (const int*)d_in[7];
    float* out = (float*)d_out;

    snn_kernel<<<dim3(NS), dim3(256), 0, stream>>>(ic, w, mu, v0, i0, s0,
                                                   reset_s, t1p, out);
}

// Round 5
// 159.116 us; speedup vs baseline: 1.0289x; 1.0289x over previous
//
#include <hip/hip_runtime.h>
#include <math.h>

#define NN 256
#define NS 512
#define MS 32
#define NSTEP 32
#define VRESET 1.0f

__device__ __forceinline__ float sigf(float x) {
    // fast sigmoid: v_exp_f32 + v_rcp_f32 (~3 ulp); verified no event flips
    // (absmax identical to OCML expf version: 0.125).
    float e = __expf(-x);
    return __builtin_amdgcn_rcpf(1.0f + e);
}

// Barrier WITHOUT the vmcnt(0) drain that __syncthreads() emits.
// LDS-only visibility; global stores/loads deliberately stay in flight.
__device__ __forceinline__ void block_sync_lds() {
    asm volatile("s_waitcnt lgkmcnt(0)" ::: "memory");
    __builtin_amdgcn_s_barrier();
    asm volatile("" ::: "memory");
}

// One RK4 step — op-for-op identical order to the verified kernel.
__device__ __forceinline__ void rk4step(float v, float ii, float s,
                                        float ic, float mu1, float mu2,
                                        float dt, float hh, float h6,
                                        float& vn, float& in_, float& sn)
{
    float kv1 = mu1 * (ii + ic - v);
    float ki1 = -mu2 * ii;
    float ks1 = sigf(v);
    float v2 = v + hh * kv1;
    float i2 = ii + hh * ki1;
    float kv2 = mu1 * (i2 + ic - v2);
    float ki2 = -mu2 * i2;
    float ks2 = sigf(v2);
    float v3 = v + hh * kv2;
    float i3 = ii + hh * ki2;
    float kv3 = mu1 * (i3 + ic - v3);
    float ki3 = -mu2 * i3;
    float ks3 = sigf(v3);
    float v4 = v + dt * kv3;
    float i4 = ii + dt * ki3;
    float kv4 = mu1 * (i4 + ic - v4);
    float ki4 = -mu2 * i4;
    float ks4 = sigf(v4);
    vn  = v  + h6 * (kv1 + 2.0f * kv2 + 2.0f * kv3 + kv4);
    in_ = ii + h6 * (ki1 + 2.0f * ki2 + 2.0f * ki3 + ki4);
    sn  = s  + h6 * (ks1 + 2.0f * ks2 + 2.0f * ks3 + ks4);
}

// R5 (value-identical to R2; R4 windowing reverted — rounds are 1-3 steps,
// unconditional window work was a 2.75x VALU regression):
// BARRIER-FREE per-step rendezvous via tagged LDS mailboxes, lag 2.
// Iteration st: issue read of slot st-2; compute y_st; publish own crossing
// bit tagged (r*33+st)<<1|bit; check slot st-2 (rare s_sleep poll). Events
// interpolate y_{j-1}<->y_j from a 4-deep register ring (A,B,P,C) — no
// replay. Liveness: resolution is deterministic & in-order, so every wave
// writes flag(q) before any wave can poll it; slot reuse across rounds is
// gated by exactly one barrier per round (event path, or a liveness barrier
// on no-event rounds). Tags are unique per (r,st) and nonzero, so stale
// entries never match. All 2048 waves are co-resident (VGPR/LDS fit), so
// polls always terminate. Barriers/round: ~k (per-step) -> 1.
__global__ __launch_bounds__(256) void snn_kernel(
    const float* __restrict__ ic_g,     // (256,)
    const float* __restrict__ w,        // (256,256)
    const float* __restrict__ mu,       // (2,)
    const float* __restrict__ v0,       // (256,)
    const float* __restrict__ i0,       // (256,)
    const float* __restrict__ s0,       // (512,256)
    const float* __restrict__ reset_s,  // (32,512,256)
    const int*   __restrict__ t1p,      // scalar
    float* __restrict__ out)
{
    const int tid  = threadIdx.x;   // neuron index
    const int lane = tid & 63;
    const int wid  = tid >> 6;
    const int samp = blockIdx.x;
    const float mu1 = mu[0];
    const float mu2 = mu[1];
    const float t1f = (float)t1p[0];

    __shared__ int4  mb4[NSTEP + 1];              // mailbox: slot st, 4 waves
    __shared__ float s_sn[NN];                    // sn at event
    __shared__ float s_sp[NN];                    // s_prev at event
    __shared__ unsigned long long s_key[4];       // per-wave argmax key
    __shared__ int   s_eidx[4];                   // per-wave min crossed idx

    // mailbox init (tags are nonzero; 0 = never-written)
    if (tid < NSTEP + 1) mb4[tid] = make_int4(0, 0, 0, 0);
    __syncthreads();

    float v  = v0[tid];
    float ii = i0[tid];
    float s  = s0[samp * NN + tid];
    const float ic = ic_g[tid];
    float t0 = 0.0f;

    float* times = out;                                  // [NS][MS]
    float* vals  = out + (size_t)NS * MS;                // [NS][MS][NN][3]
    float* marks = out + (size_t)NS * MS * (1 + NN * 3); // [NS][MS][NN]

    for (int r = 0; r < MS; ++r) {
        // Prefetch this round's reset row (coalesced 1 KB/block); stays in
        // flight across everything (no vmcnt-draining barriers).
        const float rs = reset_s[((size_t)r * NS + samp) * NN + tid];

        const float dt = (t1f - t0) / (float)NSTEP;
        float tev = t1f;
        float yv = v, yi = ii, ys = s;
        bool  em = false;
        bool  done = false;
        float wr = 0.0f;
        float te = t0;                                   // t at y_{slot-1}
        float ev_pv = 0.f, ev_pi = 0.f, ev_ps = 0.f;     // y_{j-1}
        float ev_cv = 0.f, ev_ci = 0.f, ev_cs = 0.f;     // y_j

        if (dt != 0.0f) {
            const float hh = 0.5f * dt;
            const float h6 = dt * (1.0f / 6.0f);
            const int keybase = r * (NSTEP + 1);

            // state ring: A=y_{st-3}, B=y_{st-2}, P=y_{st-1}, C=y_st
            float Av = 0.f, Ai = 0.f, As = 0.f;
            float Bv = 0.f, Bi = 0.f, Bs = 0.f;
            float Pv = v, Pi = ii, Ps = s;
            float Cv, Ci, Cs;

            // prologue st=1,2: publish flags, no resolve yet
#pragma unroll
            for (int st = 1; st <= 2; ++st) {
                rk4step(Pv, Pi, Ps, ic, mu1, mu2, dt, hh, h6, Cv, Ci, Cs);
                unsigned long long bl = __ballot(Cs > 0.0f);
                int val = ((keybase + st) << 1) | ((bl != 0ull) ? 1 : 0);
                if (lane == 0) ((volatile int*)&mb4[st])[wid] = val;
                Av = Bv; Ai = Bi; As = Bs;
                Bv = Pv; Bi = Pi; Bs = Ps;
                Pv = Cv; Pi = Ci; Ps = Cs;
            }

            for (int st = 3; st <= NSTEP; ++st) {
                const int slot = st - 2;
                volatile int* mbr = (volatile int*)&mb4[slot];
                // issue slot read early; latency hides under the RK4
                int f0 = mbr[0], f1 = mbr[1], f2 = mbr[2], f3 = mbr[3];

                rk4step(Pv, Pi, Ps, ic, mu1, mu2, dt, hh, h6, Cv, Ci, Cs);

                unsigned long long bl = __ballot(Cs > 0.0f);
                int val = ((keybase + st) << 1) | ((bl != 0ull) ? 1 : 0);
                if (lane == 0) ((volatile int*)&mb4[st])[wid] = val;

                const int key = keybase + slot;
                while (!(((f0 >> 1) == key) & ((f1 >> 1) == key) &
                         ((f2 >> 1) == key) & ((f3 >> 1) == key))) {
                    __builtin_amdgcn_s_sleep(1);
                    f0 = mbr[0]; f1 = mbr[1]; f2 = mbr[2]; f3 = mbr[3];
                }
                if (((f0 | f1 | f2 | f3) & 1) != 0) {
                    // event at step j=slot: y_{j-1}=A, y_j=B (pre-rotate)
                    ev_pv = Av; ev_pi = Ai; ev_ps = As;
                    ev_cv = Bv; ev_ci = Bi; ev_cs = Bs;
                    done = true;
                    break;
                }
                te += dt;

                Av = Bv; Ai = Bi; As = Bs;
                Bv = Pv; Bi = Pi; Bs = Ps;
                Pv = Cv; Pi = Ci; Ps = Cs;
            }

            if (!done) {
                // tail resolves: slots 31,32. Ring now: A=y30, B=y31, P=y32.
                {
                    const int slot = NSTEP - 1;
                    const int key = keybase + slot;
                    volatile int* mbr = (volatile int*)&mb4[slot];
                    int f0 = mbr[0], f1 = mbr[1], f2 = mbr[2], f3 = mbr[3];
                    while (!(((f0 >> 1) == key) & ((f1 >> 1) == key) &
                             ((f2 >> 1) == key) & ((f3 >> 1) == key))) {
                        __builtin_amdgcn_s_sleep(1);
                        f0 = mbr[0]; f1 = mbr[1]; f2 = mbr[2]; f3 = mbr[3];
                    }
                    if (((f0 | f1 | f2 | f3) & 1) != 0) {
                        ev_pv = Av; ev_pi = Ai; ev_ps = As;
                        ev_cv = Bv; ev_ci = Bi; ev_cs = Bs;
                        done = true;
                    } else {
                        te += dt;
                    }
                }
                if (!done) {
                    const int slot = NSTEP;
                    const int key = keybase + slot;
                    volatile int* mbr = (volatile int*)&mb4[slot];
                    int f0 = mbr[0], f1 = mbr[1], f2 = mbr[2], f3 = mbr[3];
                    while (!(((f0 >> 1) == key) & ((f1 >> 1) == key) &
                             ((f2 >> 1) == key) & ((f3 >> 1) == key))) {
                        __builtin_amdgcn_s_sleep(1);
                        f0 = mbr[0]; f1 = mbr[1]; f2 = mbr[2]; f3 = mbr[3];
                    }
                    if (((f0 | f1 | f2 | f3) & 1) != 0) {
                        ev_pv = Bv; ev_pi = Bi; ev_ps = Bs;
                        ev_cv = Pv; ev_ci = Pi; ev_cs = Ps;
                        done = true;
                    }
                }
            }

            if (done) {
                // ---- event: identical math to the verified kernel ----
                bool crossed = ev_cs > 0.0f;
                s_sn[tid] = ev_cs;
                s_sp[tid] = ev_ps;

                // packed argmax key: value desc, index asc on ties
                unsigned int b = __float_as_uint(ev_cs);
                unsigned int msk = (b & 0x80000000u) ? 0xFFFFFFFFu
                                                     : 0x80000000u;
                unsigned long long key =
                    ((unsigned long long)(b ^ msk) << 32) |
                    (unsigned int)(NN - 1 - tid);
#pragma unroll
                for (int off = 32; off >= 1; off >>= 1) {
                    unsigned long long o = __shfl_xor(key, off);
                    key = (o > key) ? o : key;
                }
                // fused per-wave min crossed index
                unsigned long long bm = __ballot(crossed);
                int cand = (bm != 0ull)
                               ? (wid * 64 + (int)__builtin_ctzll(bm))
                               : (2 * NN);
                if (lane == 0) { s_key[wid] = key; s_eidx[wid] = cand; }
                block_sync_lds();   // the round's one barrier (event rounds)

                unsigned long long k0 = s_key[0], k1 = s_key[1];
                unsigned long long k2 = s_key[2], k3 = s_key[3];
                k0 = (k1 > k0) ? k1 : k0;
                k2 = (k3 > k2) ? k3 : k2;
                k0 = (k2 > k0) ? k2 : k0;
                int bn = NN - 1 - (int)(unsigned int)(k0 & 0xFFFFFFFFull);

                int eidx = s_eidx[0];
                eidx = (s_eidx[1] < eidx) ? s_eidx[1] : eidx;
                eidx = (s_eidx[2] < eidx) ? s_eidx[2] : eidx;
                eidx = (s_eidx[3] < eidx) ? s_eidx[3] : eidx;

                // issue the w-row load early; L2 latency hides under interp
                wr = w[eidx * NN + tid];

                float bv  = s_sn[bn];
                float bsp = s_sp[bn];
                float frac = bsp / (bsp - bv + 1e-12f);
                frac = fminf(fmaxf(frac, 0.0f), 1.0f);
                tev = te + frac * dt;
                yv = ev_pv + frac * (ev_cv - ev_pv);
                yi = ev_pi + frac * (ev_ci - ev_pi);
                ys = ev_ps + frac * (ev_cs - ev_ps);
                em = crossed;
            } else {
                yv = Pv; yi = Pi; ys = Ps;   // full 32 steps, no event
                block_sync_lds();   // liveness barrier: gate mailbox reuse
            }
        }

        // ---- emit round outputs (stores stay in flight across barriers) ----
        const int sr = samp * MS + r;
        if (tid == 0) times[sr] = tev;
        {
            float* p = vals + ((size_t)sr * NN + tid) * 3;
            p[0] = yv;
            p[1] = yi;
            p[2] = ys;
            marks[(size_t)sr * NN + tid] = em ? 1.0f : 0.0f;
        }

        // ---- reset for next round ----
        if (done) {
            v  = yv - (em ? VRESET : 0.0f);
            ii = yi + wr;
            float sres = em ? rs : ys;
            s = fminf(sres, 0.0f);
        } else {
            v = yv; ii = yi;
            s = fminf(ys, 0.0f);
        }
        t0 = tev;
    }
}

extern "C" void kernel_launch(void* const* d_in, const int* in_sizes, int n_in,
                              void* d_out, int out_size, void* d_ws, size_t ws_size,
                              hipStream_t stream) {
    const float* ic      = (const float*)d_in[0];
    const float* w       = (const float*)d_in[1];
    const float* mu      = (const float*)d_in[2];
    const float* v0      = (const float*)d_in[3];
    const float* i0      = (const float*)d_in[4];
    const float* s0      = (const float*)d_in[5];
    const float* reset_s = (const float*)d_in[6];
    const int*   t1p     = (const int*)d_in[7];
    float* out = (float*)d_out;

    snn_kernel<<<dim3(NS), dim3(256), 0, stream>>>(ic, w, mu, v0, i0, s0,
                                                   reset_s, t1p, out);
}

// Round 6
// 132.881 us; speedup vs baseline: 1.2320x; 1.1974x over previous
//
#include <hip/hip_runtime.h>
#include <math.h>

#define NN 256
#define NS 512
#define MS 32
#define NSTEP 32
#define VRESET 1.0f

__device__ __forceinline__ float sigf(float x) {
    // fast sigmoid: v_exp_f32 + v_rcp_f32 (~3 ulp); verified no event flips
    // (absmax identical to OCML expf version: 0.125).
    float e = __expf(-x);
    return __builtin_amdgcn_rcpf(1.0f + e);
}

// Barrier WITHOUT the vmcnt(0) drain that __syncthreads() emits.
// LDS-only visibility; global stores/loads deliberately stay in flight.
__device__ __forceinline__ void block_sync_lds() {
    asm volatile("s_waitcnt lgkmcnt(0)" ::: "memory");
    __builtin_amdgcn_s_barrier();
    asm volatile("" ::: "memory");
}

// One RK4 step — op-for-op identical order to the verified kernel.
__device__ __forceinline__ void rk4step(float v, float ii, float s,
                                        float ic, float mu1, float mu2,
                                        float dt, float hh, float h6,
                                        float& vn, float& in_, float& sn)
{
    float kv1 = mu1 * (ii + ic - v);
    float ki1 = -mu2 * ii;
    float ks1 = sigf(v);
    float v2 = v + hh * kv1;
    float i2 = ii + hh * ki1;
    float kv2 = mu1 * (i2 + ic - v2);
    float ki2 = -mu2 * i2;
    float ks2 = sigf(v2);
    float v3 = v + hh * kv2;
    float i3 = ii + hh * ki2;
    float kv3 = mu1 * (i3 + ic - v3);
    float ki3 = -mu2 * i3;
    float ks3 = sigf(v3);
    float v4 = v + dt * kv3;
    float i4 = ii + dt * ki3;
    float kv4 = mu1 * (i4 + ic - v4);
    float ki4 = -mu2 * i4;
    float ks4 = sigf(v4);
    vn  = v  + h6 * (kv1 + 2.0f * kv2 + 2.0f * kv3 + kv4);
    in_ = ii + h6 * (ki1 + 2.0f * ki2 + 2.0f * ki3 + ki4);
    sn  = s  + h6 * (ks1 + 2.0f * ks2 + 2.0f * ks3 + ks4);
}

// One block (256 threads = 4 waves) per sample; thread tid owns neuron tid.
// R6 = R2 skeleton (per-step rendezvous, spec-split RK4 around the barrier;
// R4 windowing and R5 mailboxes reverted — rounds are 1-2 steps, extra
// speculative steps lose) with the EVENT PATH rewritten:
//  - per step, each thread publishes cs/ps into round-parity dbuf'd
//    s_sn/s_sp[r&1][tid]; lane0's flag now carries (min_crossed_tid<<1)|any.
//  - on event: eidx comes straight from the 4 flag metas (no ballot round,
//    no 2nd barrier) -> w[eidx] row load issues ~400cy earlier;
//    block argmax of cs is computed redundantly & identically per wave from
//    s_sn (1x ds_read_b128/lane + 6-level 32-bit shfl_xor max butterfly +
//    ballot/ctz/readlane for the first-max index) — replaces the u64
//    butterfly (12 serial bpermutes) + LDS key merge + barrier.
//  - round-parity dbuf makes the barrier-free event read race-safe: any
//    conflicting write (round r+2) is separated from the round-r read by a
//    round-r+1 step barrier both waves must cross.
//  - advance guarded by st+1<NSTEP: no-event rounds exit with y_32
//    (reference-exact; R2 latently exited with y_33, numerically invisible
//    because no-event rounds have tiny dt).
__global__ __launch_bounds__(256) void snn_kernel(
    const float* __restrict__ ic_g,     // (256,)
    const float* __restrict__ w,        // (256,256)
    const float* __restrict__ mu,       // (2,)
    const float* __restrict__ v0,       // (256,)
    const float* __restrict__ i0,       // (256,)
    const float* __restrict__ s0,       // (512,256)
    const float* __restrict__ reset_s,  // (32,512,256)
    const int*   __restrict__ t1p,      // scalar
    float* __restrict__ out)
{
    const int tid  = threadIdx.x;   // neuron index
    const int lane = tid & 63;
    const int wid  = tid >> 6;
    const int samp = blockIdx.x;
    const float mu1 = mu[0];
    const float mu2 = mu[1];
    const float t1f = (float)t1p[0];

    __shared__ int4 s_flag[4];                     // per-step meta, st&3 rot
    __shared__ __align__(16) float s_sn[2][NN];    // cs, round-parity dbuf
    __shared__ __align__(16) float s_sp[2][NN];    // ps, round-parity dbuf

    float v  = v0[tid];
    float ii = i0[tid];
    float s  = s0[samp * NN + tid];
    const float ic = ic_g[tid];
    float t0 = 0.0f;

    float* times = out;                                  // [NS][MS]
    float* vals  = out + (size_t)NS * MS;                // [NS][MS][NN][3]
    float* marks = out + (size_t)NS * MS * (1 + NN * 3); // [NS][MS][NN]

    for (int r = 0; r < MS; ++r) {
        const int buf = r & 1;
        // Prefetch this round's reset row (coalesced 1 KB/block); stays in
        // flight across barriers (no vmcnt drain in block_sync_lds).
        const float rs = reset_s[((size_t)r * NS + samp) * NN + tid];

        const float dt = (t1f - t0) / (float)NSTEP;
        float tev = t1f;
        float yv = v, yi = ii, ys = s;
        bool  em = false;
        bool  done = false;
        float wr = 0.0f;

        if (dt != 0.0f) {
            const float hh = 0.5f * dt;
            const float h6 = dt * (1.0f / 6.0f);

            // pipeline: P = y_st, C = y_{st+1}
            float pv = v, pi_ = ii, ps = s;
            float cv, ci, cs;
            rk4step(pv, pi_, ps, ic, mu1, mu2, dt, hh, h6, cv, ci, cs);
            float t = t0;

            for (int st = 0; st < NSTEP; ++st) {
                // 1) publish step-st data: per-neuron cs/ps + per-wave meta
                s_sn[buf][tid] = cs;
                s_sp[buf][tid] = ps;
                unsigned long long bl = __ballot(cs > 0.0f);
                if (lane == 0) {
                    int meta = (bl != 0ull)
                        ? ((((wid << 6) + (int)__builtin_ctzll(bl)) << 1) | 1)
                        : 0;
                    ((int*)&s_flag[st & 3])[wid] = meta;
                }

                // 2a) spec y_{st+2} first half — covers ds_write drain+barrier
                float kv1 = mu1 * (ci + ic - cv);
                float ki1 = -mu2 * ci;
                float ks1 = sigf(cv);
                float v2 = cv + hh * kv1;
                float i2 = ci + hh * ki1;
                float kv2 = mu1 * (i2 + ic - v2);
                float ki2 = -mu2 * i2;
                float ks2 = sigf(v2);

                __builtin_amdgcn_sched_barrier(0);
                block_sync_lds();
                __builtin_amdgcn_sched_barrier(0);

                // 3) flag read (uniform addr -> broadcast ds_read_b128)...
                int4 f = s_flag[st & 3];

                // 2b) ...covered by spec second half
                float v3 = cv + hh * kv2;
                float i3 = ci + hh * ki2;
                float kv3 = mu1 * (i3 + ic - v3);
                float ki3 = -mu2 * i3;
                float ks3 = sigf(v3);
                float v4 = cv + dt * kv3;
                float i4 = ci + dt * ki3;
                float kv4 = mu1 * (i4 + ic - v4);
                float ki4 = -mu2 * i4;
                float ks4 = sigf(v4);
                float nv  = cv + h6 * (kv1 + 2.0f * kv2 + 2.0f * kv3 + kv4);
                float ni  = ci + h6 * (ki1 + 2.0f * ki2 + 2.0f * ki3 + ki4);
                float ns_ = cs + h6 * (ks1 + 2.0f * ks2 + 2.0f * ks3 + ks4);

                if ((f.x | f.y | f.z | f.w) & 1) {
                    // ---- event at step st ----
                    // issue the 256-value argmax read early
                    const float4 q =
                        *(const float4*)&s_sn[buf][lane << 2];
                    // eidx straight from metas; issue w-row load NOW
                    int e0 = (f.x & 1) ? (f.x >> 1) : (2 * NN);
                    int e1 = (f.y & 1) ? (f.y >> 1) : (2 * NN);
                    int e2 = (f.z & 1) ? (f.z >> 1) : (2 * NN);
                    int e3 = (f.w & 1) ? (f.w >> 1) : (2 * NN);
                    int ea = e0 < e1 ? e0 : e1;
                    int eb = e2 < e3 ? e2 : e3;
                    int eidx = ea < eb ? ea : eb;
                    wr = w[eidx * NN + tid];

                    // block argmax (identical redundant reduce in each wave):
                    // ordered-key map (monotonic float->u32)
                    unsigned bx = __float_as_uint(q.x);
                    unsigned by = __float_as_uint(q.y);
                    unsigned bz = __float_as_uint(q.z);
                    unsigned bw = __float_as_uint(q.w);
                    unsigned k0 = (bx & 0x80000000u) ? ~bx : (bx | 0x80000000u);
                    unsigned k1 = (by & 0x80000000u) ? ~by : (by | 0x80000000u);
                    unsigned k2 = (bz & 0x80000000u) ? ~bz : (bz | 0x80000000u);
                    unsigned k3 = (bw & 0x80000000u) ? ~bw : (bw | 0x80000000u);
                    unsigned km = k0; int pos = 0;
                    if (k1 > km) { km = k1; pos = 1; }   // strict >: first max
                    if (k2 > km) { km = k2; pos = 2; }
                    if (k3 > km) { km = k3; pos = 3; }
                    unsigned red = km;
#pragma unroll
                    for (int off = 32; off >= 1; off >>= 1) {
                        unsigned o = __shfl_xor(red, off);
                        red = (o > red) ? o : red;
                    }
                    unsigned long long cm = __ballot(km == red);
                    int L = (int)__builtin_ctzll(cm);        // lowest lane
                    int wpos = __builtin_amdgcn_readlane(pos, L);
                    int bn = (L << 2) + wpos;                // first-max idx

                    float bv  = s_sn[buf][bn];
                    float bsp = s_sp[buf][bn];
                    float frac = bsp / (bsp - bv + 1e-12f);
                    frac = fminf(fmaxf(frac, 0.0f), 1.0f);
                    tev = t + frac * dt;
                    yv = pv  + frac * (cv - pv);
                    yi = pi_ + frac * (ci - pi_);
                    ys = ps  + frac * (cs - ps);
                    em = (cs > 0.0f);
                    done = true;
                    break;
                }

                // 4) advance pipeline (guarded: no-event rounds end at y_32)
                if (st + 1 < NSTEP) {
                    pv = cv; pi_ = ci; ps = cs;
                    cv = nv; ci = ni; cs = ns_;
                    t += dt;
                }
            }

            if (!done) { yv = cv; yi = ci; ys = cs; }  // y_32, no event
        }

        // ---- emit round outputs (stores stay in flight across barriers) ----
        const int sr = samp * MS + r;
        if (tid == 0) times[sr] = tev;
        {
            float* p = vals + ((size_t)sr * NN + tid) * 3;
            p[0] = yv;
            p[1] = yi;
            p[2] = ys;
            marks[(size_t)sr * NN + tid] = em ? 1.0f : 0.0f;
        }

        // ---- reset for next round ----
        if (done) {
            v  = yv - (em ? VRESET : 0.0f);
            ii = yi + wr;
            float sres = em ? rs : ys;
            s = fminf(sres, 0.0f);
        } else {
            v = yv; ii = yi;
            s = fminf(ys, 0.0f);
        }
        t0 = tev;
    }
}

extern "C" void kernel_launch(void* const* d_in, const int* in_sizes, int n_in,
                              void* d_out, int out_size, void* d_ws, size_t ws_size,
                              hipStream_t stream) {
    const float* ic      = (const float*)d_in[0];
    const float* w       = (const float*)d_in[1];
    const float* mu      = (const float*)d_in[2];
    const float* v0      = (const float*)d_in[3];
    const float* i0      = (const float*)d_in[4];
    const float* s0      = (const float*)d_in[5];
    const float* reset_s = (const float*)d_in[6];
    const int*   t1p     = (const int*)d_in[7];
    float* out = (float*)d_out;

    snn_kernel<<<dim3(NS), dim3(256), 0, stream>>>(ic, w, mu, v0, i0, s0,
                                                   reset_s, t1p, out);
}